// Round 1
// baseline (78.094 us; speedup 1.0000x reference)
//
#include <hip/hip_runtime.h>
#include <math.h>

#define D 256
#define Q 256
#define I 2048

typedef __attribute__((ext_vector_type(8))) short short8;
typedef __attribute__((ext_vector_type(4))) float floatx4;

__device__ __forceinline__ float wave_sum(float v) {
#pragma unroll
    for (int off = 1; off < 64; off <<= 1)
        v += __shfl_xor(v, off, 64);
    return v;
}

__device__ __forceinline__ float sigmoidf_(float x) {
    return 1.0f / (1.0f + expf(-x));
}

// fp32 -> bf16 round-to-nearest-even
__device__ __forceinline__ unsigned short f2bf(float f) {
    unsigned u = __float_as_uint(f);
    u += 0x7FFFu + ((u >> 16) & 1u);
    return (unsigned short)(u >> 16);
}

// Fused prep: blocks [0,64) = query prep (1 query/wave, exactly the old
// query_prep math); blocks [64,576) = gallery prep (1 row/wave): normalize
// + bf16 Y and Y^2, computed ONCE (old kernel recomputed it 4x per i-tile
// inside main, on the critical path before a barrier).
// 576 blocks x 256 thr -> covers all 256 CUs (old query_prep used 64).
__global__ void __launch_bounds__(256)
prep(const float* __restrict__ qf,
     const float* __restrict__ qif,
     const float* __restrict__ gal,
     const float* __restrict__ gamma,
     const float* __restrict__ beta,
     const float* __restrict__ mean,
     const float* __restrict__ var,
     unsigned short* __restrict__ PB,
     unsigned short* __restrict__ WB,
     unsigned short* __restrict__ VB,
     unsigned short* __restrict__ YB,
     unsigned short* __restrict__ Y2B,
     float* __restrict__ sq,
     float* __restrict__ ccp) {
    const int t = threadIdx.x;
    const int wv = t >> 6, l = t & 63;

    if (blockIdx.x >= 64) {
        // ---- gallery path: row i, lane holds d = 4l..4l+3 ----
        const int i = (blockIdx.x - 64) * 4 + wv;
        float4 x = ((const float4*)gal)[(size_t)i * 64 + l];
        float n = wave_sum(x.x * x.x + x.y * x.y + x.z * x.z + x.w * x.w);
        float inv = 1.0f / fmaxf(sqrtf(n), 1e-12f);
        float y0 = x.x * inv, y1 = x.y * inv, y2 = x.z * inv, y3 = x.w * inv;
        *(ushort4*)&YB[(size_t)i * D + 4 * l] =
            make_ushort4(f2bf(y0), f2bf(y1), f2bf(y2), f2bf(y3));
        *(ushort4*)&Y2B[(size_t)i * D + 4 * l] =
            make_ushort4(f2bf(y0 * y0), f2bf(y1 * y1), f2bf(y2 * y2), f2bf(y3 * y3));
        return;
    }

    // ---- query path (unchanged math) ----
    const int q = blockIdx.x * 4 + wv;
    const float4* qf4  = (const float4*)qf;
    const float4* qif4 = (const float4*)qif;
    const float4* ga4  = (const float4*)gamma;
    const float4* be4  = (const float4*)beta;
    const float4* me4  = (const float4*)mean;
    const float4* va4  = (const float4*)var;

    float4 x = qf4[(size_t)q * 64 + l];
    float nx = wave_sum(x.x * x.x + x.y * x.y + x.z * x.z + x.w * x.w);
    float inx = 1.0f / fmaxf(sqrtf(nx), 1e-12f);
    float g0 = sigmoidf_(x.x * inx * 5.0f);
    float g1 = sigmoidf_(x.y * inx * 5.0f);
    float g2 = sigmoidf_(x.z * inx * 5.0f);
    float g3 = sigmoidf_(x.w * inx * 5.0f);

    float4 y = qif4[(size_t)q * 64 + l];
    float ny = wave_sum(y.x * y.x + y.y * y.y + y.z * y.z + y.w * y.w);
    float iny = 1.0f / fmaxf(sqrtf(ny), 1e-12f);

    float4 gm = ga4[l], bt = be4[l], mn = me4[l], vr = va4[l];
    float is0 = gm.x * rsqrtf(vr.x + 1e-5f);
    float is1 = gm.y * rsqrtf(vr.y + 1e-5f);
    float is2 = gm.z * rsqrtf(vr.z + 1e-5f);
    float is3 = gm.w * rsqrtf(vr.w + 1e-5f);
    float c0 = bt.x - mn.x * is0;
    float c1 = bt.y - mn.y * is1;
    float c2 = bt.z - mn.z * is2;
    float c3 = bt.w - mn.w * is3;
    float a0 = g0 * is0, a1 = g1 * is1, a2 = g2 * is2, a3 = g3 * is3;

    float f0 = y.x * iny * a0 + c0;
    float f1 = y.y * iny * a1 + c1;
    float f2 = y.z * iny * a2 + c2;
    float f3 = y.w * iny * a3 + c3;
    float nf = wave_sum(f0 * f0 + f1 * f1 + f2 * f2 + f3 * f3);
    float inf_ = 1.0f / fmaxf(sqrtf(nf), 1e-12f);
    float u0 = f0 * inf_, u1 = f1 * inf_, u2 = f2 * inf_, u3 = f3 * inf_;

    *(ushort4*)&PB[(size_t)q * D + 4 * l] =
        make_ushort4(f2bf(u0 * a0), f2bf(u1 * a1), f2bf(u2 * a2), f2bf(u3 * a3));
    *(ushort4*)&WB[(size_t)q * D + 4 * l] =
        make_ushort4(f2bf(a0 * a0), f2bf(a1 * a1), f2bf(a2 * a2), f2bf(a3 * a3));
    *(ushort4*)&VB[(size_t)q * D + 4 * l] =
        make_ushort4(f2bf(2.0f * a0 * c0), f2bf(2.0f * a1 * c1),
                     f2bf(2.0f * a2 * c2), f2bf(2.0f * a3 * c3));

    float s = wave_sum(u0 * c0 + u1 * c1 + u2 * c2 + u3 * c3);
    if (l == 0) sq[q] = s;

    if (q == 0) {
        float ccs = wave_sum(c0 * c0 + c1 * c1 + c2 * c2 + c3 * c3);
        if (l == 0) *ccp = ccs;
    }
}

// Main: pure gather + MFMA. No LDS, no __syncthreads, no normalization.
// grid = (Q/16, I/32) = (16,64) = 1024 independent 1-wave blocks.
// Wave: 16 q x 32 i (2 sub-tiles of 16 i), K=256.
//   acc1[i,q] = sum_k Y[i,k]  * P[q,k]
//   acc2[i,q] = sum_k Y2[i,k] * W[q,k] + Y[i,k] * V[q,k]
// All operands are bf16 in L2 (~3.4 MB total) -> load latency hidden by
// deep unrolled load lists + 4 blocks/CU.
__global__ void __launch_bounds__(64)
main_scores(const unsigned short* __restrict__ YB,
            const unsigned short* __restrict__ Y2B,
            const unsigned short* __restrict__ PB,
            const unsigned short* __restrict__ WB,
            const unsigned short* __restrict__ VB,
            const float* __restrict__ sq,
            const float* __restrict__ ccp,
            float* __restrict__ out) {
    const int l = threadIdx.x;
    const int lm = l & 15, quad = l >> 4, koff = quad * 8;
    const int q0 = blockIdx.x * 16, i0 = blockIdx.y * 32;
    const int qr = q0 + lm;

    // B-frags: full K=256 for this wave's 16 query rows.
    short8 bp[8], bw[8], bv[8];
#pragma unroll
    for (int ks = 0; ks < 8; ks++) {
        const size_t o = (size_t)qr * D + ks * 32 + koff;
        bp[ks] = *(const short8*)&PB[o];
        bw[ks] = *(const short8*)&WB[o];
        bv[ks] = *(const short8*)&VB[o];
    }
    const float sqv = sq[qr];
    const float ccv = *ccp;

#pragma unroll
    for (int it = 0; it < 2; it++) {
        const int ir = i0 + it * 16 + lm;
        floatx4 acc1 = {0.f, 0.f, 0.f, 0.f};
        floatx4 acc2 = {0.f, 0.f, 0.f, 0.f};
#pragma unroll
        for (int ks = 0; ks < 8; ks++) {
            const size_t o = (size_t)ir * D + ks * 32 + koff;
            short8 ay  = *(const short8*)&YB[o];
            short8 ay2 = *(const short8*)&Y2B[o];
            acc1 = __builtin_amdgcn_mfma_f32_16x16x32_bf16(ay,  bp[ks], acc1, 0, 0, 0);
            acc2 = __builtin_amdgcn_mfma_f32_16x16x32_bf16(ay2, bw[ks], acc2, 0, 0, 0);
            acc2 = __builtin_amdgcn_mfma_f32_16x16x32_bf16(ay,  bv[ks], acc2, 0, 0, 0);
        }
        float4 o4;
        float* po = &o4.x;
#pragma unroll
        for (int rr = 0; rr < 4; rr++) {
            float nrm = fmaxf(sqrtf(fmaxf(acc2[rr] + ccv, 0.f)), 1e-12f);
            po[rr] = sigmoidf_((acc1[rr] + sqv) / nrm);
        }
        *(float4*)&out[(size_t)qr * I + i0 + it * 16 + quad * 4] = o4;
    }
}

extern "C" void kernel_launch(void* const* d_in, const int* in_sizes, int n_in,
                              void* d_out, int out_size, void* d_ws, size_t ws_size,
                              hipStream_t stream) {
    const float* qf    = (const float*)d_in[0]; // [Q,D]
    const float* qif   = (const float*)d_in[1]; // [Q,D]
    const float* gal   = (const float*)d_in[2]; // [I,D]
    const float* gamma = (const float*)d_in[3];
    const float* beta  = (const float*)d_in[4];
    const float* mean  = (const float*)d_in[5];
    const float* var   = (const float*)d_in[6];
    float* out = (float*)d_out;                 // [Q,I]

    char* base = (char*)d_ws;
    float* sq = (float*)base;                               // Q floats
    float* cc = (float*)(base + 1024);                      // 1 float
    unsigned short* PB = (unsigned short*)(base + 2048);    // Q*D bf16
    unsigned short* WB = PB + (size_t)Q * D;
    unsigned short* VB = WB + (size_t)Q * D;
    unsigned short* YB = VB + (size_t)Q * D;                // I*D bf16
    unsigned short* Y2B = YB + (size_t)I * D;

    prep<<<576, 256, 0, stream>>>(qf, qif, gal, gamma, beta, mean, var,
                                  PB, WB, VB, YB, Y2B, sq, cc);
    main_scores<<<dim3(Q / 16, I / 32), 64, 0, stream>>>(YB, Y2B, PB, WB, VB,
                                                         sq, cc, out);
}